// Round 2
// baseline (674.554 us; speedup 1.0000x reference)
//
#include <hip/hip_runtime.h>
#include <stdint.h>

#define DD 160
#define HH 160
#define WW 160
#define NGRID (DD*HH*WW)
#define CIN 32
#define COUT 64
#define KK 27

typedef __bf16 bf16x8 __attribute__((ext_vector_type(8)));
typedef float f32x16 __attribute__((ext_vector_type(16)));

__device__ __forceinline__ uint32_t f2bf(float f) {
    uint32_t u = __float_as_uint(f);
    return (u + 0x7fffu + ((u >> 16) & 1u)) >> 16;   // RNE
}

__device__ __forceinline__ bf16x8 as_bf16x8(uint4 u) {
    union { uint4 u; bf16x8 v; } x; x.u = u; return x.v;
}

__global__ void scatter_grid(const int4* __restrict__ coors, int* __restrict__ grid, int n) {
    int i = blockIdx.x * 256 + threadIdx.x;
    if (i < n) {
        int4 c = coors[i];
        grid[(c.y * HH + c.z) * WW + c.w] = i;
    }
}

// features f32 [n][32] -> bf16 rows of 64B, plus one zero row at index n
__global__ void cvt_feats(const float4* __restrict__ f4, uint2* __restrict__ fb, int nq) {
    int t = blockIdx.x * 256 + threadIdx.x;
    if (t >= nq + 8) return;
    uint2 r = {0u, 0u};
    if (t < nq) {
        float4 f = f4[t];
        r.x = f2bf(f.x) | (f2bf(f.y) << 16);
        r.y = f2bf(f.z) | (f2bf(f.w) << 16);
    }
    fb[t] = r;
}

// W f32 [k][ci][co] -> per-lane B-fragments for mfma_f32_32x32x16_bf16
// layout: wf[((k*2+s)*2+cot)*64 + lane] = uint4 of 8 bf16,
//   element j = W[k][s*16 + (lane>>5)*8 + j][cot*32 + (lane&31)]
__global__ void pack_bfrag(const float* __restrict__ w, uint4* __restrict__ wf) {
    int t = blockIdx.x * 256 + threadIdx.x;
    if (t >= KK * 2 * 2 * 64) return;
    int lane = t & 63;
    int cot  = (t >> 6) & 1;
    int s    = (t >> 7) & 1;
    int k    = t >> 8;
    int ncol = cot * 32 + (lane & 31);
    int cib  = s * 16 + (lane >> 5) * 8;
    const float* base = w + ((size_t)k * CIN + cib) * COUT + ncol;
    uint32_t h[8];
    #pragma unroll
    for (int j = 0; j < 8; ++j) h[j] = f2bf(base[(size_t)j * COUT]);
    uint4 r;
    r.x = h[0] | (h[1] << 16);
    r.y = h[2] | (h[3] << 16);
    r.z = h[4] | (h[5] << 16);
    r.w = h[6] | (h[7] << 16);
    wf[t] = r;
}

// one wave per 32-voxel tile; lane: m = lane&31 (voxel row / cout col), half = lane>>5
__global__ __launch_bounds__(1024, 4) void sparse_conv_mfma(
    const uint2* __restrict__ fb,      // (n+1) rows x 64B bf16
    const int4* __restrict__ coors,
    const float* __restrict__ bias,
    const uint4* __restrict__ wf,
    const int* __restrict__ grid,
    float* __restrict__ out, int n)
{
    __shared__ uint4 blds[KK * 4 * 64];   // 110,592 B

    for (int t = threadIdx.x; t < KK * 4 * 64; t += 1024) blds[t] = wf[t];
    __syncthreads();

    const int lane = threadIdx.x & 63;
    const int wv   = threadIdx.x >> 6;
    const int m    = lane & 31;
    const int half = lane >> 5;

    const float bias0 = bias[m];
    const float bias1 = bias[32 + m];

    const int ntiles = (n + 31) >> 5;
    const bf16x8* fbase = (const bf16x8*)fb;

    for (int tile = blockIdx.x * 16 + wv; tile < ntiles; tile += gridDim.x * 16) {
        const int vbase = tile << 5;
        const int v = vbase + m;
        const bool vm = v < n;
        int4 c = coors[vm ? v : 0];

        // all 27x32 probes in 14 parallel 64-lane rounds; result registers
        int p[14];
        #pragma unroll
        for (int r = 0; r < 14; ++r) {
            const int k = r * 2 + half;
            int res = n;                       // zero row
            if (k < KK && vm) {
                const int dz = k / 9 - 1;
                const int dy = (k / 3) % 3 - 1;
                const int dx = k - (k / 3) * 3 - 1;
                const int nz = c.y + dz, ny = c.z + dy, nx = c.w + dx;
                if ((unsigned)nz < (unsigned)DD && (unsigned)ny < (unsigned)HH &&
                    (unsigned)nx < (unsigned)WW) {
                    const int g = grid[(nz * HH + ny) * WW + nx];
                    if (g >= 0) res = g;
                }
            }
            p[r] = res;
        }

        f32x16 acc0, acc1;
        #pragma unroll
        for (int i = 0; i < 16; ++i) { acc0[i] = 0.f; acc1[i] = 0.f; }

        #pragma unroll
        for (int k = 0; k < KK; ++k) {
            // neighbor index for (k, voxel m): probe idx k*32+m lives in lane (k&1)*32+m, reg k>>1
            const int j = __shfl(p[k >> 1], ((k & 1) << 5) | m, 64);
            const size_t rowb = (size_t)j * 4;          // 4 x 16B chunks per 64B row
            bf16x8 a0 = fbase[rowb + half];             // ci 0..15  (this half's 8)
            bf16x8 a1 = fbase[rowb + 2 + half];         // ci 16..31
            const uint4* bp = &blds[k * 256 + lane];
            bf16x8 b00 = as_bf16x8(bp[0]);              // s=0, cot=0
            bf16x8 b01 = as_bf16x8(bp[64]);             // s=0, cot=1
            bf16x8 b10 = as_bf16x8(bp[128]);            // s=1, cot=0
            bf16x8 b11 = as_bf16x8(bp[192]);            // s=1, cot=1
            acc0 = __builtin_amdgcn_mfma_f32_32x32x16_bf16(a0, b00, acc0, 0, 0, 0);
            acc1 = __builtin_amdgcn_mfma_f32_32x32x16_bf16(a0, b01, acc1, 0, 0, 0);
            acc0 = __builtin_amdgcn_mfma_f32_32x32x16_bf16(a1, b10, acc0, 0, 0, 0);
            acc1 = __builtin_amdgcn_mfma_f32_32x32x16_bf16(a1, b11, acc1, 0, 0, 0);
        }

        // C/D: col = lane&31, row = (reg&3) + 8*(reg>>2) + 4*(lane>>5)   [m74/m101]
        if (vbase + 32 <= n) {
            #pragma unroll
            for (int r = 0; r < 16; ++r) {
                const int row = (r & 3) + 8 * (r >> 2) + 4 * half;
                float* o = out + (size_t)(vbase + row) * COUT;
                o[m]      = acc0[r] + bias0;
                o[32 + m] = acc1[r] + bias1;
            }
        } else {
            #pragma unroll
            for (int r = 0; r < 16; ++r) {
                const int row = (r & 3) + 8 * (r >> 2) + 4 * half;
                if (vbase + row < n) {
                    float* o = out + (size_t)(vbase + row) * COUT;
                    o[m]      = acc0[r] + bias0;
                    o[32 + m] = acc1[r] + bias1;
                }
            }
        }
    }
}

extern "C" void kernel_launch(void* const* d_in, const int* in_sizes, int n_in,
                              void* d_out, int out_size, void* d_ws, size_t ws_size,
                              hipStream_t stream) {
    const float* feats  = (const float*)d_in[0];
    const int*   coors  = (const int*)d_in[1];
    const float* weight = (const float*)d_in[2];
    const float* bias   = (const float*)d_in[3];
    float*       outp   = (float*)d_out;

    const int n = in_sizes[1] / 4;   // 400000

    char*  ws   = (char*)d_ws;
    int*   grid = (int*)ws;
    uint2* fb   = (uint2*)(ws + (size_t)NGRID * 4);
    uint4* wfp  = (uint4*)(ws + (size_t)NGRID * 4 + (size_t)(n + 1) * 64);

    hipMemsetAsync(grid, 0xFF, (size_t)NGRID * 4, stream);
    scatter_grid<<<(n + 255) / 256, 256, 0, stream>>>((const int4*)coors, grid, n);

    const int nq = n * 8;
    cvt_feats<<<(nq + 8 + 255) / 256, 256, 0, stream>>>((const float4*)feats, fb, nq);
    pack_bfrag<<<(KK * 4 * 64 + 255) / 256, 256, 0, stream>>>(weight, wfp);

    sparse_conv_mfma<<<256, 1024, 0, stream>>>(fb, (const int4*)coors, bias, wfp, grid, outp, n);
}

// Round 3
// 669.032 us; speedup vs baseline: 1.0083x; 1.0083x over previous
//
#include <hip/hip_runtime.h>
#include <stdint.h>

#define DD 160
#define HH 160
#define WW 160
#define NCELL (DD*HH*WW)      // 4,096,000
#define CIN 32
#define COUT 64
#define KK 27
#define CPB 1024              // cells per compaction chunk
#define NCHUNK (NCELL/CPB)    // 4000 exactly

typedef __bf16 bf16x8 __attribute__((ext_vector_type(8)));
typedef float f32x16 __attribute__((ext_vector_type(16)));

__device__ __forceinline__ uint32_t f2bf(float f) {
    uint32_t u = __float_as_uint(f);
    return (u + 0x7fffu + ((u >> 16) & 1u)) >> 16;   // RNE
}
__device__ __forceinline__ bf16x8 as_bf16x8(uint4 u) {
    union { uint4 u; bf16x8 v; } x; x.u = u; return x.v;
}

__global__ void scatter_grid(const int4* __restrict__ coors, int* __restrict__ grid, int n) {
    int i = blockIdx.x * 256 + threadIdx.x;
    if (i < n) {
        int4 c = coors[i];
        grid[(c.y * HH + c.z) * WW + c.w] = i;
    }
}

__global__ void count_chunks(const int* __restrict__ grid, int* __restrict__ bcount) {
    __shared__ int s[256];
    const int t = threadIdx.x;
    const int* g = grid + blockIdx.x * CPB + t * 4;
    int c = 0;
    #pragma unroll
    for (int j = 0; j < 4; ++j) c += (g[j] >= 0);
    s[t] = c; __syncthreads();
    for (int off = 128; off; off >>= 1) {
        if (t < off) s[t] += s[t + off];
        __syncthreads();
    }
    if (t == 0) bcount[blockIdx.x] = s[0];
}

// single block: exclusive scan of NCHUNK (=4000) chunk counts
__global__ void scan_chunks(const int* __restrict__ bcount, int* __restrict__ bbase) {
    __shared__ int s[1024];
    const int t = threadIdx.x;
    int v[4]; int sum = 0;
    #pragma unroll
    for (int j = 0; j < 4; ++j) {
        int idx = t * 4 + j;
        v[j] = (idx < NCHUNK) ? bcount[idx] : 0;
        sum += v[j];
    }
    s[t] = sum; __syncthreads();
    for (int off = 1; off < 1024; off <<= 1) {
        int x = (t >= off) ? s[t - off] : 0;
        __syncthreads();
        s[t] += x;
        __syncthreads();
    }
    int run = s[t] - sum;   // exclusive
    #pragma unroll
    for (int j = 0; j < 4; ++j) {
        int idx = t * 4 + j;
        if (idx < NCHUNK) bbase[idx] = run;
        run += v[j];
    }
}

// order-preserving compaction: grid[cell] id -> sorted pos; emit sid, scoors
__global__ void scatter_sorted(int* __restrict__ grid, const int* __restrict__ bbase,
                               const int4* __restrict__ coors,
                               int* __restrict__ sid, int4* __restrict__ scoors) {
    __shared__ int s[256];
    const int t = threadIdx.x;
    int* g = grid + blockIdx.x * CPB + t * 4;
    int id[4]; int c = 0;
    #pragma unroll
    for (int j = 0; j < 4; ++j) { id[j] = g[j]; c += (id[j] >= 0); }
    s[t] = c; __syncthreads();
    for (int off = 1; off < 256; off <<= 1) {
        int x = (t >= off) ? s[t - off] : 0;
        __syncthreads();
        s[t] += x;
        __syncthreads();
    }
    int pos = bbase[blockIdx.x] + s[t] - c;
    #pragma unroll
    for (int j = 0; j < 4; ++j) {
        if (id[j] >= 0) {
            sid[pos] = id[j];
            scoors[pos] = coors[id[j]];
            g[j] = pos;
            pos++;
        }
    }
}

// sfeat[pos] = bf16(features[sid[pos]]); zero row at pos==n
__global__ void gather_feats(const float4* __restrict__ feats, const int* __restrict__ sid,
                             uint2* __restrict__ sfeat, int n) {
    int t = blockIdx.x * 256 + threadIdx.x;
    if (t >= (n + 1) * 8) return;
    int pos = t >> 3, c = t & 7;
    uint2 r = {0u, 0u};
    if (pos < n) {
        int id = sid[pos];
        float4 f = feats[(size_t)id * 8 + c];
        r.x = f2bf(f.x) | (f2bf(f.y) << 16);
        r.y = f2bf(f.z) | (f2bf(f.w) << 16);
    }
    sfeat[t] = r;
}

// W f32 [k][ci][co] -> per-lane B-fragments for mfma_f32_32x32x16_bf16
__global__ void pack_bfrag(const float* __restrict__ w, uint4* __restrict__ wf) {
    int t = blockIdx.x * 256 + threadIdx.x;
    if (t >= KK * 2 * 2 * 64) return;
    int lane = t & 63;
    int cot  = (t >> 6) & 1;
    int s    = (t >> 7) & 1;
    int k    = t >> 8;
    int ncol = cot * 32 + (lane & 31);
    int cib  = s * 16 + (lane >> 5) * 8;
    const float* base = w + ((size_t)k * CIN + cib) * COUT + ncol;
    uint32_t h[8];
    #pragma unroll
    for (int j = 0; j < 8; ++j) h[j] = f2bf(base[(size_t)j * COUT]);
    uint4 r;
    r.x = h[0] | (h[1] << 16);
    r.y = h[2] | (h[3] << 16);
    r.z = h[4] | (h[5] << 16);
    r.w = h[6] | (h[7] << 16);
    wf[t] = r;
}

// one wave per 32-sorted-voxel tile; contiguous tile chunks per block
__global__ __launch_bounds__(1024, 4) void sparse_conv_mfma(
    const uint2* __restrict__ sfeat,
    const int4* __restrict__ scoors,
    const int*  __restrict__ sid,
    const float* __restrict__ bias,
    const uint4* __restrict__ wf,
    const int* __restrict__ grid,     // holds sorted pos
    float* __restrict__ out, int n)
{
    __shared__ uint4 blds[KK * 4 * 64];   // 110,592 B

    for (int t = threadIdx.x; t < KK * 4 * 64; t += 1024) blds[t] = wf[t];
    __syncthreads();

    const int lane = threadIdx.x & 63;
    const int wv   = threadIdx.x >> 6;
    const int m    = lane & 31;
    const int half = lane >> 5;

    const float bias0 = bias[m];
    const float bias1 = bias[32 + m];

    const int ntiles = (n + 31) >> 5;
    const int tpb = (ntiles + gridDim.x - 1) / gridDim.x;
    const int t0 = blockIdx.x * tpb;
    const int t1 = min(t0 + tpb, ntiles);
    const bf16x8* fbase = (const bf16x8*)sfeat;

    for (int tile = t0 + wv; tile < t1; tile += 16) {
        const int vbase = tile << 5;
        const int v = vbase + m;
        const bool vm = v < n;
        int4 c = scoors[vm ? v : 0];

        // 27x32 probes in 14 parallel 64-lane rounds
        int p[14];
        #pragma unroll
        for (int r = 0; r < 14; ++r) {
            const int k = r * 2 + half;
            int res = n;                       // zero row
            if (k < KK && vm) {
                const int dz = k / 9 - 1;
                const int dy = (k / 3) % 3 - 1;
                const int dx = k - (k / 3) * 3 - 1;
                const int nz = c.y + dz, ny = c.z + dy, nx = c.w + dx;
                if ((unsigned)nz < (unsigned)DD && (unsigned)ny < (unsigned)HH &&
                    (unsigned)nx < (unsigned)WW) {
                    const int g = grid[(nz * HH + ny) * WW + nx];
                    if (g >= 0) res = g;
                }
            }
            p[r] = res;
        }

        f32x16 acc0, acc1;
        #pragma unroll
        for (int i = 0; i < 16; ++i) { acc0[i] = 0.f; acc1[i] = 0.f; }

        // depth-2 software pipeline on the A-fragment gathers
        bf16x8 pa0[2], pa1[2];
        {
            int j = __shfl(p[0], m, 64);               // k=0
            pa0[0] = fbase[(size_t)j * 4 + half];
            pa1[0] = fbase[(size_t)j * 4 + 2 + half];
            j = __shfl(p[0], 32 | m, 64);              // k=1
            pa0[1] = fbase[(size_t)j * 4 + half];
            pa1[1] = fbase[(size_t)j * 4 + 2 + half];
        }

        #pragma unroll
        for (int k = 0; k < KK; ++k) {
            bf16x8 a0 = pa0[k & 1], a1 = pa1[k & 1];
            if (k + 2 < KK) {
                const int kk = k + 2;
                int j = __shfl(p[kk >> 1], ((kk & 1) << 5) | m, 64);
                pa0[k & 1] = fbase[(size_t)j * 4 + half];
                pa1[k & 1] = fbase[(size_t)j * 4 + 2 + half];
            }
            const uint4* bp = &blds[k * 256 + lane];
            bf16x8 b00 = as_bf16x8(bp[0]);
            bf16x8 b01 = as_bf16x8(bp[64]);
            bf16x8 b10 = as_bf16x8(bp[128]);
            bf16x8 b11 = as_bf16x8(bp[192]);
            acc0 = __builtin_amdgcn_mfma_f32_32x32x16_bf16(a0, b00, acc0, 0, 0, 0);
            acc1 = __builtin_amdgcn_mfma_f32_32x32x16_bf16(a0, b01, acc1, 0, 0, 0);
            acc0 = __builtin_amdgcn_mfma_f32_32x32x16_bf16(a1, b10, acc0, 0, 0, 0);
            acc1 = __builtin_amdgcn_mfma_f32_32x32x16_bf16(a1, b11, acc1, 0, 0, 0);
        }

        // sid for output rows (original voxel ids)
        int sv = 0;
        {
            int idx = vbase + m;
            if (idx < n) sv = sid[idx];
        }

        // C/D: col = lane&31, row = (reg&3) + 8*(reg>>2) + 4*(lane>>5)
        #pragma unroll
        for (int r = 0; r < 16; ++r) {
            const int row = (r & 3) + 8 * (r >> 2) + 4 * half;
            if (vbase + row < n) {
                const int orig = __shfl(sv, row, 64);
                float* o = out + (size_t)orig * COUT;
                o[m]      = acc0[r] + bias0;
                o[32 + m] = acc1[r] + bias1;
            }
        }
    }
}

extern "C" void kernel_launch(void* const* d_in, const int* in_sizes, int n_in,
                              void* d_out, int out_size, void* d_ws, size_t ws_size,
                              hipStream_t stream) {
    const float* feats  = (const float*)d_in[0];
    const int*   coors  = (const int*)d_in[1];
    const float* weight = (const float*)d_in[2];
    const float* bias   = (const float*)d_in[3];
    float*       outp   = (float*)d_out;

    const int n = in_sizes[1] / 4;   // 400000

    char* ws = (char*)d_ws;
    size_t off = 0;
    int*   grid   = (int*)(ws + off);   off += (size_t)NCELL * 4;          // 16,384,000
    uint2* sfeat  = (uint2*)(ws + off); off += (size_t)(n + 1) * 64;       // 25,600,064
    int4*  scoors = (int4*)(ws + off);  off += (size_t)n * 16;             // 6,400,000
    int*   sid    = (int*)(ws + off);   off += (size_t)n * 4;              // 1,600,000
    uint4* wfp    = (uint4*)(ws + off); off += (size_t)KK * 4 * 64 * 16;   // 110,592
    int*   bcount = (int*)(ws + off);   off += (size_t)NCHUNK * 4;
    int*   bbase  = (int*)(ws + off);   off += (size_t)NCHUNK * 4;

    hipMemsetAsync(grid, 0xFF, (size_t)NCELL * 4, stream);
    scatter_grid<<<(n + 255) / 256, 256, 0, stream>>>((const int4*)coors, grid, n);
    count_chunks<<<NCHUNK, 256, 0, stream>>>(grid, bcount);
    scan_chunks<<<1, 1024, 0, stream>>>(bcount, bbase);
    scatter_sorted<<<NCHUNK, 256, 0, stream>>>(grid, bbase, (const int4*)coors, sid, scoors);
    gather_feats<<<((n + 1) * 8 + 255) / 256, 256, 0, stream>>>((const float4*)feats, sid, sfeat, n);
    pack_bfrag<<<(KK * 4 * 64 + 255) / 256, 256, 0, stream>>>(weight, wfp);

    sparse_conv_mfma<<<256, 1024, 0, stream>>>(sfeat, (const int4*)scoors, sid, bias, wfp, grid, outp, n);
}

// Round 4
// 647.452 us; speedup vs baseline: 1.0419x; 1.0333x over previous
//
#include <hip/hip_runtime.h>
#include <stdint.h>

#define DD 160
#define HH 160
#define WW 160
#define NCELL (DD*HH*WW)      // 4,096,000
#define CIN 32
#define COUT 64
#define KK 27
#define CPB 1024              // cells per compaction chunk
#define NCHUNK (NCELL/CPB)    // 4000 exactly

typedef __bf16 bf16x8 __attribute__((ext_vector_type(8)));
typedef float f32x16 __attribute__((ext_vector_type(16)));

__device__ __forceinline__ uint32_t f2bf(float f) {
    uint32_t u = __float_as_uint(f);
    return (u + 0x7fffu + ((u >> 16) & 1u)) >> 16;   // RNE
}
__device__ __forceinline__ bf16x8 as_bf16x8(uint4 u) {
    union { uint4 u; bf16x8 v; } x; x.u = u; return x.v;
}

__global__ void scatter_grid(const int4* __restrict__ coors, int* __restrict__ grid, int n) {
    int i = blockIdx.x * 256 + threadIdx.x;
    if (i < n) {
        int4 c = coors[i];
        grid[(c.y * HH + c.z) * WW + c.w] = i;
    }
}

__global__ void count_chunks(const int* __restrict__ grid, int* __restrict__ bcount) {
    __shared__ int s[256];
    const int t = threadIdx.x;
    const int* g = grid + blockIdx.x * CPB + t * 4;
    int c = 0;
    #pragma unroll
    for (int j = 0; j < 4; ++j) c += (g[j] >= 0);
    s[t] = c; __syncthreads();
    for (int off = 128; off; off >>= 1) {
        if (t < off) s[t] += s[t + off];
        __syncthreads();
    }
    if (t == 0) bcount[blockIdx.x] = s[0];
}

// single block: exclusive scan of NCHUNK (=4000) chunk counts
__global__ void scan_chunks(const int* __restrict__ bcount, int* __restrict__ bbase) {
    __shared__ int s[1024];
    const int t = threadIdx.x;
    int v[4]; int sum = 0;
    #pragma unroll
    for (int j = 0; j < 4; ++j) {
        int idx = t * 4 + j;
        v[j] = (idx < NCHUNK) ? bcount[idx] : 0;
        sum += v[j];
    }
    s[t] = sum; __syncthreads();
    for (int off = 1; off < 1024; off <<= 1) {
        int x = (t >= off) ? s[t - off] : 0;
        __syncthreads();
        s[t] += x;
        __syncthreads();
    }
    int run = s[t] - sum;   // exclusive
    #pragma unroll
    for (int j = 0; j < 4; ++j) {
        int idx = t * 4 + j;
        if (idx < NCHUNK) bbase[idx] = run;
        run += v[j];
    }
}

// order-preserving compaction: grid[cell] id -> sorted pos; emit sid, scoors
__global__ void scatter_sorted(int* __restrict__ grid, const int* __restrict__ bbase,
                               const int4* __restrict__ coors,
                               int* __restrict__ sid, int4* __restrict__ scoors) {
    __shared__ int s[256];
    const int t = threadIdx.x;
    int* g = grid + blockIdx.x * CPB + t * 4;
    int id[4]; int c = 0;
    #pragma unroll
    for (int j = 0; j < 4; ++j) { id[j] = g[j]; c += (id[j] >= 0); }
    s[t] = c; __syncthreads();
    for (int off = 1; off < 256; off <<= 1) {
        int x = (t >= off) ? s[t - off] : 0;
        __syncthreads();
        s[t] += x;
        __syncthreads();
    }
    int pos = bbase[blockIdx.x] + s[t] - c;
    #pragma unroll
    for (int j = 0; j < 4; ++j) {
        if (id[j] >= 0) {
            sid[pos] = id[j];
            scoors[pos] = coors[id[j]];
            g[j] = pos;
            pos++;
        }
    }
}

// sfeat[pos] = bf16(features[sid[pos]]); zero row at pos==n
__global__ void gather_feats(const float4* __restrict__ feats, const int* __restrict__ sid,
                             uint2* __restrict__ sfeat, int n) {
    int t = blockIdx.x * 256 + threadIdx.x;
    if (t >= (n + 1) * 8) return;
    int pos = t >> 3, c = t & 7;
    uint2 r = {0u, 0u};
    if (pos < n) {
        int id = sid[pos];
        float4 f = feats[(size_t)id * 8 + c];
        r.x = f2bf(f.x) | (f2bf(f.y) << 16);
        r.y = f2bf(f.z) | (f2bf(f.w) << 16);
    }
    sfeat[t] = r;
}

// W f32 [k][ci][co] -> per-lane B-fragments for mfma_f32_32x32x16_bf16
__global__ void pack_bfrag(const float* __restrict__ w, uint4* __restrict__ wf) {
    int t = blockIdx.x * 256 + threadIdx.x;
    if (t >= KK * 2 * 2 * 64) return;
    int lane = t & 63;
    int cot  = (t >> 6) & 1;
    int s    = (t >> 7) & 1;
    int k    = t >> 8;
    int ncol = cot * 32 + (lane & 31);
    int cib  = s * 16 + (lane >> 5) * 8;
    const float* base = w + ((size_t)k * CIN + cib) * COUT + ncol;
    uint32_t h[8];
    #pragma unroll
    for (int j = 0; j < 8; ++j) h[j] = f2bf(base[(size_t)j * COUT]);
    uint4 r;
    r.x = h[0] | (h[1] << 16);
    r.y = h[2] | (h[3] << 16);
    r.z = h[4] | (h[5] << 16);
    r.w = h[6] | (h[7] << 16);
    wf[t] = r;
}

// one wave per 32-sorted-voxel tile; XCD-contiguous block chunks
__global__ __launch_bounds__(1024, 4) void sparse_conv_mfma(
    const uint2* __restrict__ sfeat,
    const int4* __restrict__ scoors,
    const int*  __restrict__ sid,
    const float* __restrict__ bias,
    const uint4* __restrict__ wf,
    const int* __restrict__ grid,     // holds sorted pos
    float* __restrict__ out, int n)
{
    __shared__ uint4 blds[KK * 4 * 64];   // 110,592 B
    __shared__ float olds[16 * 8 * 64];   //  32,768 B (2 KB per wave)

    for (int t = threadIdx.x; t < KK * 4 * 64; t += 1024) blds[t] = wf[t];
    __syncthreads();

    const int lane = threadIdx.x & 63;
    const int wv   = threadIdx.x >> 6;
    const int m    = lane & 31;
    const int half = lane >> 5;

    const float biasL = bias[lane];

    // XCD-contiguous mapping: blocks b with b%8==x (same XCD) get a
    // contiguous range of tiles so each XCD's L2 sees one compact region.
    const int l = (blockIdx.x & 7) * 32 + (blockIdx.x >> 3);

    const int ntiles = (n + 31) >> 5;
    const int tpb = (ntiles + gridDim.x - 1) / gridDim.x;
    const int t0 = l * tpb;
    const int t1 = min(t0 + tpb, ntiles);
    const bf16x8* fbase = (const bf16x8*)sfeat;
    float* ob = &olds[wv * 512];

    for (int tile = t0 + wv; tile < t1; tile += 16) {
        const int vbase = tile << 5;
        const int v = vbase + m;
        const bool vm = v < n;

        // issue sid load early (needed only in epilogue)
        int sv = 0;
        if (vm) sv = sid[v];

        int4 c = scoors[vm ? v : 0];

        // 27x32 probes in 14 parallel 64-lane rounds
        int p[14];
        #pragma unroll
        for (int r = 0; r < 14; ++r) {
            const int k = r * 2 + half;
            int res = n;                       // zero row
            if (k < KK && vm) {
                const int dz = k / 9 - 1;
                const int dy = (k / 3) % 3 - 1;
                const int dx = k - (k / 3) * 3 - 1;
                const int nz = c.y + dz, ny = c.z + dy, nx = c.w + dx;
                if ((unsigned)nz < (unsigned)DD && (unsigned)ny < (unsigned)HH &&
                    (unsigned)nx < (unsigned)WW) {
                    const int g = grid[(nz * HH + ny) * WW + nx];
                    if (g >= 0) res = g;
                }
            }
            p[r] = res;
        }

        f32x16 acc0, acc1;
        #pragma unroll
        for (int i = 0; i < 16; ++i) { acc0[i] = 0.f; acc1[i] = 0.f; }

        // depth-4 software pipeline on the A-fragment gathers
        bf16x8 pa0[4], pa1[4];
        #pragma unroll
        for (int k = 0; k < 4; ++k) {
            int j = __shfl(p[k >> 1], ((k & 1) << 5) | m, 64);
            pa0[k] = fbase[(size_t)j * 4 + half];
            pa1[k] = fbase[(size_t)j * 4 + 2 + half];
        }

        #pragma unroll
        for (int k = 0; k < KK; ++k) {
            bf16x8 a0 = pa0[k & 3], a1 = pa1[k & 3];
            if (k + 4 < KK) {
                const int kk = k + 4;
                int j = __shfl(p[kk >> 1], ((kk & 1) << 5) | m, 64);
                pa0[k & 3] = fbase[(size_t)j * 4 + half];
                pa1[k & 3] = fbase[(size_t)j * 4 + 2 + half];
            }
            const uint4* bp = &blds[k * 256 + lane];
            bf16x8 b00 = as_bf16x8(bp[0]);
            bf16x8 b01 = as_bf16x8(bp[64]);
            bf16x8 b10 = as_bf16x8(bp[128]);
            bf16x8 b11 = as_bf16x8(bp[192]);
            acc0 = __builtin_amdgcn_mfma_f32_32x32x16_bf16(a0, b00, acc0, 0, 0, 0);
            acc1 = __builtin_amdgcn_mfma_f32_32x32x16_bf16(a0, b01, acc1, 0, 0, 0);
            acc0 = __builtin_amdgcn_mfma_f32_32x32x16_bf16(a1, b10, acc0, 0, 0, 0);
            acc1 = __builtin_amdgcn_mfma_f32_32x32x16_bf16(a1, b11, acc1, 0, 0, 0);
        }

        // epilogue: wave-synchronous LDS transpose -> one 256B row per store.
        // C/D: col = lane&31, row = (reg&3) + 8*(reg>>2) + 4*(lane>>5)
        #pragma unroll
        for (int pss = 0; pss < 4; ++pss) {
            #pragma unroll
            for (int rr = 0; rr < 4; ++rr) {
                const int r = 4 * pss + rr;
                const int rl = rr + 4 * half;            // local row 0..7
                ob[rl * 64 + m]      = acc0[r];
                ob[rl * 64 + 32 + m] = acc1[r];
            }
            #pragma unroll
            for (int q = 0; q < 8; ++q) {
                const int row = vbase + 8 * pss + q;
                if (row < n) {
                    const int orig = __shfl(sv, 8 * pss + q, 64);
                    out[(size_t)orig * COUT + lane] = ob[q * 64 + lane] + biasL;
                }
            }
        }
    }
}

extern "C" void kernel_launch(void* const* d_in, const int* in_sizes, int n_in,
                              void* d_out, int out_size, void* d_ws, size_t ws_size,
                              hipStream_t stream) {
    const float* feats  = (const float*)d_in[0];
    const int*   coors  = (const int*)d_in[1];
    const float* weight = (const float*)d_in[2];
    const float* bias   = (const float*)d_in[3];
    float*       outp   = (float*)d_out;

    const int n = in_sizes[1] / 4;   // 400000

    char* ws = (char*)d_ws;
    size_t off = 0;
    int*   grid   = (int*)(ws + off);   off += (size_t)NCELL * 4;
    uint2* sfeat  = (uint2*)(ws + off); off += (size_t)(n + 1) * 64;
    int4*  scoors = (int4*)(ws + off);  off += (size_t)n * 16;
    int*   sid    = (int*)(ws + off);   off += (size_t)n * 4;
    uint4* wfp    = (uint4*)(ws + off); off += (size_t)KK * 4 * 64 * 16;
    int*   bcount = (int*)(ws + off);   off += (size_t)NCHUNK * 4;
    int*   bbase  = (int*)(ws + off);   off += (size_t)NCHUNK * 4;

    hipMemsetAsync(grid, 0xFF, (size_t)NCELL * 4, stream);
    scatter_grid<<<(n + 255) / 256, 256, 0, stream>>>((const int4*)coors, grid, n);
    count_chunks<<<NCHUNK, 256, 0, stream>>>(grid, bcount);
    scan_chunks<<<1, 1024, 0, stream>>>(bcount, bbase);
    scatter_sorted<<<NCHUNK, 256, 0, stream>>>(grid, bbase, (const int4*)coors, sid, scoors);
    gather_feats<<<((n + 1) * 8 + 255) / 256, 256, 0, stream>>>((const float4*)feats, sid, sfeat, n);
    pack_bfrag<<<(KK * 4 * 64 + 255) / 256, 256, 0, stream>>>(weight, wfp);

    sparse_conv_mfma<<<256, 1024, 0, stream>>>(sfeat, (const int4*)scoors, sid, bias, wfp, grid, outp, n);
}